// Round 1
// baseline (2496.996 us; speedup 1.0000x reference)
//
#include <hip/hip_runtime.h>
#include <math.h>

#define BB 4
#define TT 24
#define BN 1024
#define FD 128
#define BT (BB*TT)
#define BTN (BT*BN)
#define FRONT_T 12
#define SCALE 0.08838834764831845f   // 1/sqrt(128)
#define GELU_K 0.7071067811865476f   // 1/sqrt(2)

// ---------------------------------------------------------------------------
// Kernel 1: x_ = input @ W_xff.T + b_xff  -> split into q,k,v
// Tiles: 32 rows x 64 cols, K=128 fully resident in LDS.
// ---------------------------------------------------------------------------
__global__ __launch_bounds__(256) void k_qkv(const float* __restrict__ x,
                                             const float* __restrict__ W,
                                             const float* __restrict__ bias,
                                             float* __restrict__ q,
                                             float* __restrict__ k,
                                             float* __restrict__ v) {
    __shared__ float Xs[32][129];  // pad 1: scalar reads conflict-free
    __shared__ float Ws[64][129];
    const int tid = threadIdx.x;
    const int rowBase = blockIdx.x * 32;       // input row tile
    const int colBase = blockIdx.y * 64;       // output col tile (0..383)

    for (int i = 0; i < 4; ++i) {              // 32x128 = 1024 float4
        int idx = i * 256 + tid;
        int r = idx >> 5, c4 = idx & 31;
        *(float4*)(&Xs[r][c4 * 4]) = *(const float4*)(x + (size_t)(rowBase + r) * FD + c4 * 4);
    }
    for (int i = 0; i < 8; ++i) {              // 64x128 = 2048 float4
        int idx = i * 256 + tid;
        int r = idx >> 5, c4 = idx & 31;
        *(float4*)(&Ws[r][c4 * 4]) = *(const float4*)(W + (size_t)(colBase + r) * FD + c4 * 4);
    }
    __syncthreads();

    const int tx = tid & 15, ty = tid >> 4;
    const int r0 = ty * 2, r1 = ty * 2 + 1;
    float acc0[4] = {0.f, 0.f, 0.f, 0.f};
    float acc1[4] = {0.f, 0.f, 0.f, 0.f};
    for (int kk = 0; kk < FD; ++kk) {
        float a0 = Xs[r0][kk], a1 = Xs[r1][kk];
        float b0 = Ws[tx * 4 + 0][kk];
        float b1 = Ws[tx * 4 + 1][kk];
        float b2 = Ws[tx * 4 + 2][kk];
        float b3 = Ws[tx * 4 + 3][kk];
        acc0[0] += a0 * b0; acc0[1] += a0 * b1; acc0[2] += a0 * b2; acc0[3] += a0 * b3;
        acc1[0] += a1 * b0; acc1[1] += a1 * b1; acc1[2] += a1 * b2; acc1[3] += a1 * b3;
    }
    const int c = colBase + tx * 4;
    float4 bia = *(const float4*)(bias + c);
    float4 o0 = make_float4(acc0[0] + bia.x, acc0[1] + bia.y, acc0[2] + bia.z, acc0[3] + bia.w);
    float4 o1 = make_float4(acc1[0] + bia.x, acc1[1] + bia.y, acc1[2] + bia.z, acc1[3] + bia.w);
    float* base;
    int cc;
    if (c < FD)           { base = q; cc = c; }
    else if (c < 2 * FD)  { base = k; cc = c - FD; }
    else                  { base = v; cc = c - 2 * FD; }
    *(float4*)(base + (size_t)(rowBase + r0) * FD + cc) = o0;
    *(float4*)(base + (size_t)(rowBase + r1) * FD + cc) = o1;
}

// ---------------------------------------------------------------------------
// Kernel 2: per-row softmax statistics M (rowmax of e) and L (sum exp(e-M)),
// online over 16 column tiles of 64. e = q.k^T * SCALE.
// ---------------------------------------------------------------------------
__global__ __launch_bounds__(256) void k_pass1(const float* __restrict__ q,
                                               const float* __restrict__ kmat,
                                               float* __restrict__ Mv,
                                               float* __restrict__ Lv) {
    __shared__ float Qs[32][129];
    __shared__ float Ks[64][129];
    const int tid = threadIdx.x;
    const int bt = blockIdx.y;
    const int rowBase = blockIdx.x * 32;
    const float* qb = q + (size_t)bt * BN * FD;
    const float* kb = kmat + (size_t)bt * BN * FD;

    for (int i = 0; i < 4; ++i) {
        int idx = i * 256 + tid;
        int r = idx >> 5, c4 = idx & 31;
        *(float4*)(&Qs[r][c4 * 4]) = *(const float4*)(qb + (size_t)(rowBase + r) * FD + c4 * 4);
    }
    const int tx = tid & 15, ty = tid >> 4;
    const int r0 = ty * 2, r1 = ty * 2 + 1;
    float m[2] = {-1e30f, -1e30f};
    float l[2] = {0.f, 0.f};

    for (int ct = 0; ct < 16; ++ct) {
        __syncthreads();
        for (int i = 0; i < 8; ++i) {
            int idx = i * 256 + tid;
            int r = idx >> 5, c4 = idx & 31;
            *(float4*)(&Ks[r][c4 * 4]) = *(const float4*)(kb + (size_t)(ct * 64 + r) * FD + c4 * 4);
        }
        __syncthreads();
        float e0[4] = {0.f, 0.f, 0.f, 0.f};
        float e1[4] = {0.f, 0.f, 0.f, 0.f};
        for (int kk = 0; kk < FD; ++kk) {
            float a0 = Qs[r0][kk], a1 = Qs[r1][kk];
            float b0 = Ks[tx * 4 + 0][kk];
            float b1 = Ks[tx * 4 + 1][kk];
            float b2 = Ks[tx * 4 + 2][kk];
            float b3 = Ks[tx * 4 + 3][kk];
            e0[0] += a0 * b0; e0[1] += a0 * b1; e0[2] += a0 * b2; e0[3] += a0 * b3;
            e1[0] += a1 * b0; e1[1] += a1 * b1; e1[2] += a1 * b2; e1[3] += a1 * b3;
        }
        float* ep[2] = {e0, e1};
        for (int rr = 0; rr < 2; ++rr) {
            float s0 = ep[rr][0] * SCALE, s1 = ep[rr][1] * SCALE;
            float s2 = ep[rr][2] * SCALE, s3 = ep[rr][3] * SCALE;
            float tm = fmaxf(fmaxf(s0, s1), fmaxf(s2, s3));
            for (int s = 1; s < 16; s <<= 1) tm = fmaxf(tm, __shfl_xor(tm, s, 64));
            float ts = __expf(s0 - tm) + __expf(s1 - tm) + __expf(s2 - tm) + __expf(s3 - tm);
            for (int s = 1; s < 16; s <<= 1) ts += __shfl_xor(ts, s, 64);
            float mn = fmaxf(m[rr], tm);
            l[rr] = l[rr] * __expf(m[rr] - mn) + ts * __expf(tm - mn);
            m[rr] = mn;
        }
    }
    if (tx == 0) {
        Mv[(size_t)bt * BN + rowBase + r0] = m[0];
        Lv[(size_t)bt * BN + rowBase + r0] = l[0];
        Mv[(size_t)bt * BN + rowBase + r1] = m[1];
        Lv[(size_t)bt * BN + rowBase + r1] = l[1];
    }
}

// ---------------------------------------------------------------------------
// Kernel 3: column sums of attn at t = T-1 only (needed for y_last).
// Block owns 64 columns, streams all 1024 rows in 32-row tiles.
// ---------------------------------------------------------------------------
__global__ __launch_bounds__(256) void k_colsum(const float* __restrict__ q,
                                                const float* __restrict__ kmat,
                                                const float* __restrict__ Mv,
                                                const float* __restrict__ Lv,
                                                float* __restrict__ cs) {
    __shared__ float Qs[32][129];
    __shared__ float Ks[64][129];
    __shared__ float red[16][68];
    const int tid = threadIdx.x;
    const int b = blockIdx.y;
    const int bt = b * TT + (TT - 1);
    const int colBase = blockIdx.x * 64;
    const float* qb = q + (size_t)bt * BN * FD;
    const float* kb = kmat + (size_t)bt * BN * FD;
    const int tx = tid & 15, ty = tid >> 4;
    const int r0 = ty * 2, r1 = ty * 2 + 1;

    for (int i = 0; i < 8; ++i) {                 // K tile fixed for the block
        int idx = i * 256 + tid;
        int r = idx >> 5, c4 = idx & 31;
        *(float4*)(&Ks[r][c4 * 4]) = *(const float4*)(kb + (size_t)(colBase + r) * FD + c4 * 4);
    }

    float acc[4] = {0.f, 0.f, 0.f, 0.f};
    for (int rt = 0; rt < 32; ++rt) {
        __syncthreads();
        for (int i = 0; i < 4; ++i) {
            int idx = i * 256 + tid;
            int r = idx >> 5, c4 = idx & 31;
            *(float4*)(&Qs[r][c4 * 4]) = *(const float4*)(qb + (size_t)(rt * 32 + r) * FD + c4 * 4);
        }
        __syncthreads();
        float e0[4] = {0.f, 0.f, 0.f, 0.f};
        float e1[4] = {0.f, 0.f, 0.f, 0.f};
        for (int kk = 0; kk < FD; ++kk) {
            float a0 = Qs[r0][kk], a1 = Qs[r1][kk];
            float b0 = Ks[tx * 4 + 0][kk];
            float b1 = Ks[tx * 4 + 1][kk];
            float b2 = Ks[tx * 4 + 2][kk];
            float b3 = Ks[tx * 4 + 3][kk];
            e0[0] += a0 * b0; e0[1] += a0 * b1; e0[2] += a0 * b2; e0[3] += a0 * b3;
            e1[0] += a1 * b0; e1[1] += a1 * b1; e1[2] += a1 * b2; e1[3] += a1 * b3;
        }
        int n0 = rt * 32 + r0, n1 = rt * 32 + r1;
        float m0 = Mv[(size_t)bt * BN + n0], il0 = 1.0f / Lv[(size_t)bt * BN + n0];
        float m1 = Mv[(size_t)bt * BN + n1], il1 = 1.0f / Lv[(size_t)bt * BN + n1];
        for (int j = 0; j < 4; ++j) {
            acc[j] += __expf(e0[j] * SCALE - m0) * il0;
            acc[j] += __expf(e1[j] * SCALE - m1) * il1;
        }
    }
    for (int j = 0; j < 4; ++j) red[ty][tx * 4 + j] = acc[j];
    __syncthreads();
    if (tid < 64) {
        float s = 0.f;
        for (int i = 0; i < 16; ++i) s += red[i][tid];
        cs[(size_t)b * BN + colBase + tid] = s;
    }
}

// ---------------------------------------------------------------------------
// Kernel 4: index of 3rd-smallest column sum per batch (jax.lax.top_k
// tie-break: lower index wins -> lexicographic (value, index) compare).
// ---------------------------------------------------------------------------
__global__ void k_top3(const float* __restrict__ cs, int* __restrict__ ylast) {
    __shared__ float sv[192];
    __shared__ int si[192];
    const int b = blockIdx.x;
    const int t = threadIdx.x;   // 64 threads
    float bv[3] = {1e30f, 1e30f, 1e30f};
    int bi[3] = {0x7fffffff, 0x7fffffff, 0x7fffffff};
    for (int i = 0; i < 16; ++i) {
        int idx = t * 16 + i;
        float vv = cs[(size_t)b * BN + idx];
        if (vv < bv[0]) {
            bv[2] = bv[1]; bi[2] = bi[1];
            bv[1] = bv[0]; bi[1] = bi[0];
            bv[0] = vv;    bi[0] = idx;
        } else if (vv < bv[1]) {
            bv[2] = bv[1]; bi[2] = bi[1];
            bv[1] = vv;    bi[1] = idx;
        } else if (vv < bv[2]) {
            bv[2] = vv;    bi[2] = idx;
        }
    }
    for (int j = 0; j < 3; ++j) { sv[t * 3 + j] = bv[j]; si[t * 3 + j] = bi[j]; }
    __syncthreads();
    if (t == 0) {
        float fv[3] = {1e30f, 1e30f, 1e30f};
        int fi[3] = {0x7fffffff, 0x7fffffff, 0x7fffffff};
        for (int c = 0; c < 192; ++c) {
            float vv = sv[c]; int ii = si[c];
            if (vv < fv[0] || (vv == fv[0] && ii < fi[0])) {
                fv[2] = fv[1]; fi[2] = fi[1];
                fv[1] = fv[0]; fi[1] = fi[0];
                fv[0] = vv;    fi[0] = ii;
            } else if (vv < fv[1] || (vv == fv[1] && ii < fi[1])) {
                fv[2] = fv[1]; fi[2] = fi[1];
                fv[1] = vv;    fi[1] = ii;
            } else if (vv < fv[2] || (vv == fv[2] && ii < fi[2])) {
                fv[2] = vv;    fi[2] = ii;
            }
        }
        ylast[b] = fi[2];
    }
}

// ---------------------------------------------------------------------------
// Kernel 5: mixup of v row y for t < FRONT_T. Emulates numpy float->uint8
// cast: truncate toward zero, wrap mod 256.
// ---------------------------------------------------------------------------
__global__ void k_mixup(float* __restrict__ v, const int* __restrict__ ylast) {
    const int b = blockIdx.y, t = blockIdx.x, f = threadIdx.x;
    const int y = ylast[b];
    const int ys = max(y - 1, 0), ye = min(y + 2, BN);
    float s = 0.f;
    for (int r = ys; r < ye; ++r)
        s += v[(((size_t)(b * TT + t)) * BN + r) * FD + f];
    s /= (float)(ye - ys);
    int ti = (int)s;                       // trunc toward zero
    unsigned int u = ((unsigned int)ti) & 0xFFu;   // wrap mod 256 (numpy/x86)
    v[(((size_t)(b * TT + t)) * BN + y) * FD + f] = (float)u;
}

// ---------------------------------------------------------------------------
// Kernel 6: value_i = attn @ new_value (e recomputed), then FF1+gelu, FF2,
// residual, LayerNorm -- fully fused per 32-row tile.
// Thread (tx,ty): rows ty*2+{0,1}; f-columns f(j) = tx + 16*j, j in [0,8).
// ---------------------------------------------------------------------------
__global__ __launch_bounds__(256) void k_av_ffn(const float* __restrict__ q,
                                                const float* __restrict__ kmat,
                                                const float* __restrict__ v,
                                                const float* __restrict__ Mv,
                                                const float* __restrict__ Lv,
                                                const float* __restrict__ x,
                                                const float* __restrict__ W1,
                                                const float* __restrict__ b1,
                                                const float* __restrict__ W2,
                                                const float* __restrict__ b2,
                                                const float* __restrict__ g,
                                                const float* __restrict__ lb,
                                                float* __restrict__ out) {
    __shared__ float Qs[32][132];   // Q tile -> O -> h1  (pad 4: float4-friendly)
    __shared__ float KVs[64][132];  // K tile / V tile / W1 chunk / W2 chunk
    __shared__ float Ps[32][68];    // P tile
    const int tid = threadIdx.x;
    const int bt = blockIdx.y;
    const int rowBase = blockIdx.x * 32;
    const float* qb = q + (size_t)bt * BN * FD;
    const float* kb = kmat + (size_t)bt * BN * FD;
    const float* vb = v + (size_t)bt * BN * FD;
    const int tx = tid & 15, ty = tid >> 4;
    const int r0 = ty * 2, r1 = ty * 2 + 1;

    for (int i = 0; i < 4; ++i) {
        int idx = i * 256 + tid;
        int r = idx >> 5, c4 = idx & 31;
        *(float4*)(&Qs[r][c4 * 4]) = *(const float4*)(qb + (size_t)(rowBase + r) * FD + c4 * 4);
    }
    const float M0 = Mv[(size_t)bt * BN + rowBase + r0];
    const float M1 = Mv[(size_t)bt * BN + rowBase + r1];
    const float iL0 = 1.0f / Lv[(size_t)bt * BN + rowBase + r0];
    const float iL1 = 1.0f / Lv[(size_t)bt * BN + rowBase + r1];

    float o0[8] = {}, o1[8] = {};
    for (int ct = 0; ct < 16; ++ct) {
        __syncthreads();
        for (int i = 0; i < 8; ++i) {           // K tile
            int idx = i * 256 + tid;
            int r = idx >> 5, c4 = idx & 31;
            *(float4*)(&KVs[r][c4 * 4]) = *(const float4*)(kb + (size_t)(ct * 64 + r) * FD + c4 * 4);
        }
        __syncthreads();
        // e tile: cols c(jj) = tx + 16*jj (2-way-free LDS reads with pad 132)
        float e0[4] = {0.f, 0.f, 0.f, 0.f};
        float e1[4] = {0.f, 0.f, 0.f, 0.f};
        for (int kk = 0; kk < FD; ++kk) {
            float a0 = Qs[r0][kk], a1 = Qs[r1][kk];
            float c0 = KVs[tx + 0][kk];
            float c1 = KVs[tx + 16][kk];
            float c2 = KVs[tx + 32][kk];
            float c3 = KVs[tx + 48][kk];
            e0[0] += a0 * c0; e0[1] += a0 * c1; e0[2] += a0 * c2; e0[3] += a0 * c3;
            e1[0] += a1 * c0; e1[1] += a1 * c1; e1[2] += a1 * c2; e1[3] += a1 * c3;
        }
        for (int jj = 0; jj < 4; ++jj) {
            Ps[r0][tx + 16 * jj] = __expf(e0[jj] * SCALE - M0) * iL0;
            Ps[r1][tx + 16 * jj] = __expf(e1[jj] * SCALE - M1) * iL1;
        }
        __syncthreads();
        for (int i = 0; i < 8; ++i) {           // V tile (overwrite K)
            int idx = i * 256 + tid;
            int r = idx >> 5, c4 = idx & 31;
            *(float4*)(&KVs[r][c4 * 4]) = *(const float4*)(vb + (size_t)(ct * 64 + r) * FD + c4 * 4);
        }
        __syncthreads();
        for (int mm = 0; mm < 64; ++mm) {
            float p0 = Ps[r0][mm], p1 = Ps[r1][mm];
            for (int j = 0; j < 8; ++j) {
                float vv = KVs[mm][tx + 16 * j];
                o0[j] += p0 * vv;
                o1[j] += p1 * vv;
            }
        }
    }
    __syncthreads();
    for (int j = 0; j < 8; ++j) { Qs[r0][tx + 16 * j] = o0[j]; Qs[r1][tx + 16 * j] = o1[j]; }
    __syncthreads();

    // FF1: h = gelu(u @ W1^T + b1). Output f(j) = tx+16*j; chunk 0 = j<4.
    float h0[8], h1[8];
    {
        float t0[8] = {}, t1[8] = {};
        for (int ch = 0; ch < 2; ++ch) {
            __syncthreads();
            for (int i = 0; i < 8; ++i) {
                int idx = i * 256 + tid;
                int r = idx >> 5, c4 = idx & 31;
                *(float4*)(&KVs[r][c4 * 4]) = *(const float4*)(W1 + (size_t)(ch * 64 + r) * FD + c4 * 4);
            }
            __syncthreads();
            for (int kk = 0; kk < FD; ++kk) {
                float u0 = Qs[r0][kk], u1 = Qs[r1][kk];
                for (int jj = 0; jj < 4; ++jj) {
                    int j = jj + 4 * ch;
                    float w = KVs[tx + 16 * jj][kk];
                    t0[j] += u0 * w;
                    t1[j] += u1 * w;
                }
            }
        }
        for (int j = 0; j < 8; ++j) {
            int f = tx + 16 * j;
            float bj = b1[f];
            float z0 = t0[j] + bj, z1 = t1[j] + bj;
            h0[j] = 0.5f * z0 * (1.0f + erff(z0 * GELU_K));
            h1[j] = 0.5f * z1 * (1.0f + erff(z1 * GELU_K));
        }
    }
    __syncthreads();
    for (int j = 0; j < 8; ++j) { Qs[r0][tx + 16 * j] = h0[j]; Qs[r1][tx + 16 * j] = h1[j]; }
    __syncthreads();

    // FF2: z = h @ W2^T + b2
    float z0[8], z1[8];
    {
        float t0[8] = {}, t1[8] = {};
        for (int ch = 0; ch < 2; ++ch) {
            __syncthreads();
            for (int i = 0; i < 8; ++i) {
                int idx = i * 256 + tid;
                int r = idx >> 5, c4 = idx & 31;
                *(float4*)(&KVs[r][c4 * 4]) = *(const float4*)(W2 + (size_t)(ch * 64 + r) * FD + c4 * 4);
            }
            __syncthreads();
            for (int kk = 0; kk < FD; ++kk) {
                float u0 = Qs[r0][kk], u1 = Qs[r1][kk];
                for (int jj = 0; jj < 4; ++jj) {
                    int j = jj + 4 * ch;
                    float w = KVs[tx + 16 * jj][kk];
                    t0[j] += u0 * w;
                    t1[j] += u1 * w;
                }
            }
        }
        for (int j = 0; j < 8; ++j) {
            int f = tx + 16 * j;
            float bj = b2[f];
            z0[j] = t0[j] + bj;
            z1[j] = t1[j] + bj;
        }
    }

    // residual + LayerNorm over F (row spread across 16 tx lanes x 8 regs)
    const float* xb = x + ((size_t)bt * BN + rowBase) * FD;
    float res0[8], res1[8];
    float s0 = 0.f, s1 = 0.f;
    for (int j = 0; j < 8; ++j) {
        int f = tx + 16 * j;
        res0[j] = z0[j] + xb[(size_t)r0 * FD + f];
        res1[j] = z1[j] + xb[(size_t)r1 * FD + f];
        s0 += res0[j];
        s1 += res1[j];
    }
    for (int s = 1; s < 16; s <<= 1) { s0 += __shfl_xor(s0, s, 64); s1 += __shfl_xor(s1, s, 64); }
    const float mu0 = s0 * (1.0f / FD), mu1 = s1 * (1.0f / FD);
    float q0 = 0.f, q1 = 0.f;
    for (int j = 0; j < 8; ++j) {
        float d0 = res0[j] - mu0, d1 = res1[j] - mu1;
        q0 += d0 * d0;
        q1 += d1 * d1;
    }
    for (int s = 1; s < 16; s <<= 1) { q0 += __shfl_xor(q0, s, 64); q1 += __shfl_xor(q1, s, 64); }
    const float rs0 = rsqrtf(q0 * (1.0f / FD) + 1e-5f);
    const float rs1 = rsqrtf(q1 * (1.0f / FD) + 1e-5f);
    float* ob = out + ((size_t)bt * BN + rowBase) * FD;
    for (int j = 0; j < 8; ++j) {
        int f = tx + 16 * j;
        float gf = g[f], bf = lb[f];
        ob[(size_t)r0 * FD + f] = (res0[j] - mu0) * rs0 * gf + bf;
        ob[(size_t)r1 * FD + f] = (res1[j] - mu1) * rs1 * gf + bf;
    }
}

// ---------------------------------------------------------------------------
extern "C" void kernel_launch(void* const* d_in, const int* in_sizes, int n_in,
                              void* d_out, int out_size, void* d_ws, size_t ws_size,
                              hipStream_t stream) {
    const float* x     = (const float*)d_in[0];
    const float* W_xff = (const float*)d_in[1];
    const float* b_xff = (const float*)d_in[2];
    const float* W_ff1 = (const float*)d_in[3];
    const float* b_ff1 = (const float*)d_in[4];
    const float* W_ff2 = (const float*)d_in[5];
    const float* b_ff2 = (const float*)d_in[6];
    const float* ln_g  = (const float*)d_in[7];
    const float* ln_b  = (const float*)d_in[8];
    float* out = (float*)d_out;

    float* ws = (float*)d_ws;
    float* q  = ws;
    float* k  = ws + (size_t)BTN * FD;
    float* v  = ws + 2 * (size_t)BTN * FD;
    float* Mv = ws + 3 * (size_t)BTN * FD;
    float* Lv = Mv + BTN;
    float* cs = Lv + BTN;
    int* ylast = (int*)(cs + (size_t)BB * BN);

    k_qkv   <<<dim3(BTN / 32, 6),  256, 0, stream>>>(x, W_xff, b_xff, q, k, v);
    k_pass1 <<<dim3(32, BT),       256, 0, stream>>>(q, k, Mv, Lv);
    k_colsum<<<dim3(16, BB),       256, 0, stream>>>(q, k, Mv, Lv, cs);
    k_top3  <<<dim3(BB),            64, 0, stream>>>(cs, ylast);
    k_mixup <<<dim3(FRONT_T, BB),  128, 0, stream>>>(v, ylast);
    k_av_ffn<<<dim3(32, BT),       256, 0, stream>>>(q, k, v, Mv, Lv, x,
                                                     W_ff1, b_ff1, W_ff2, b_ff2,
                                                     ln_g, ln_b, out);
}

// Round 4
// 945.455 us; speedup vs baseline: 2.6411x; 2.6411x over previous
//
#include <hip/hip_runtime.h>
#include <math.h>

#define BB 4
#define TT 24
#define BN 1024
#define FD 128
#define BT (BB*TT)
#define BTN (BT*BN)
#define FRONT_T 12
#define SCALE 0.08838834764831845f   // 1/sqrt(128)
#define GELU_K 0.7071067811865476f   // 1/sqrt(2)

typedef __attribute__((ext_vector_type(8))) short s8v;   // 8 bf16 (4 VGPRs)
typedef __attribute__((ext_vector_type(4))) float f4v;   // 4 fp32 acc

static __device__ __forceinline__ unsigned short f2bf(float f) {
    union { float f; unsigned u; } c; c.f = f;
    unsigned u = c.u + 0x7FFFu + ((c.u >> 16) & 1u);   // RNE
    return (unsigned short)(u >> 16);
}

// ---------------------------------------------------------------------------
// Kernel 1: x_ = input @ W_xff.T + b_xff  (fp32 vector GEMM, known-good).
// Emits: bf16 q,k row-major; bf16 v TRANSPOSED [bt][f][n];
// fp32 q,k compact copies for bt%24==23 (y_last path);
// fp32 v compact copy for t<FRONT_T (mixup path).
// ---------------------------------------------------------------------------
__global__ __launch_bounds__(256) void k_qkv(const float* __restrict__ x,
                                             const float* __restrict__ W,
                                             const float* __restrict__ bias,
                                             unsigned short* __restrict__ qb16,
                                             unsigned short* __restrict__ kb16,
                                             unsigned short* __restrict__ vtb,
                                             float* __restrict__ q32c,
                                             float* __restrict__ k32c,
                                             float* __restrict__ v32f) {
    __shared__ float Xs[32][129];
    __shared__ float Ws[64][129];
    const int tid = threadIdx.x;
    const int rowBase = blockIdx.x * 32;
    const int colBase = blockIdx.y * 64;

    for (int i = 0; i < 4; ++i) {
        int idx = i * 256 + tid;
        int r = idx >> 5, c4 = idx & 31;
        *(float4*)(&Xs[r][c4 * 4]) = *(const float4*)(x + (size_t)(rowBase + r) * FD + c4 * 4);
    }
    for (int i = 0; i < 8; ++i) {
        int idx = i * 256 + tid;
        int r = idx >> 5, c4 = idx & 31;
        *(float4*)(&Ws[r][c4 * 4]) = *(const float4*)(W + (size_t)(colBase + r) * FD + c4 * 4);
    }
    __syncthreads();

    const int tx = tid & 15, ty = tid >> 4;
    const int r0 = ty * 2, r1 = ty * 2 + 1;
    float acc0[4] = {0.f, 0.f, 0.f, 0.f};
    float acc1[4] = {0.f, 0.f, 0.f, 0.f};
    for (int kk = 0; kk < FD; ++kk) {
        float a0 = Xs[r0][kk], a1 = Xs[r1][kk];
        float b0 = Ws[tx * 4 + 0][kk];
        float b1 = Ws[tx * 4 + 1][kk];
        float b2 = Ws[tx * 4 + 2][kk];
        float b3 = Ws[tx * 4 + 3][kk];
        acc0[0] += a0 * b0; acc0[1] += a0 * b1; acc0[2] += a0 * b2; acc0[3] += a0 * b3;
        acc1[0] += a1 * b0; acc1[1] += a1 * b1; acc1[2] += a1 * b2; acc1[3] += a1 * b3;
    }
    const int c = colBase + tx * 4;
    float4 bia = *(const float4*)(bias + c);
    float o0[4] = {acc0[0] + bia.x, acc0[1] + bia.y, acc0[2] + bia.z, acc0[3] + bia.w};
    float o1[4] = {acc1[0] + bia.x, acc1[1] + bia.y, acc1[2] + bia.z, acc1[3] + bia.w};

    const int n0 = rowBase + r0;
    const int bt = rowBase >> 10;
    const int nl = (rowBase & 1023) + r0;

    if (c < 2 * FD) {
        unsigned short* dst = (c < FD) ? qb16 : kb16;
        int cc = (c < FD) ? c : c - FD;
        ushort4 h0 = {f2bf(o0[0]), f2bf(o0[1]), f2bf(o0[2]), f2bf(o0[3])};
        ushort4 h1 = {f2bf(o1[0]), f2bf(o1[1]), f2bf(o1[2]), f2bf(o1[3])};
        *(ushort4*)(dst + (size_t)n0 * FD + cc) = h0;
        *(ushort4*)(dst + (size_t)(n0 + 1) * FD + cc) = h1;
        if ((bt % TT) == TT - 1) {
            float* d32 = (c < FD) ? q32c : k32c;
            size_t base = ((size_t)(bt / TT) * BN + nl) * FD + cc;
            *(float4*)(d32 + base)      = make_float4(o0[0], o0[1], o0[2], o0[3]);
            *(float4*)(d32 + base + FD) = make_float4(o1[0], o1[1], o1[2], o1[3]);
        }
    } else {
        int cc = c - 2 * FD;
        for (int i = 0; i < 4; ++i) {
            unsigned pk = (unsigned)f2bf(o0[i]) | ((unsigned)f2bf(o1[i]) << 16);
            *(unsigned*)(vtb + ((size_t)bt * FD + cc + i) * BN + nl) = pk;
        }
        const int tloc = bt % TT;
        if (tloc < FRONT_T) {
            float* d32 = v32f + (((size_t)(bt / TT) * FRONT_T + tloc) * BN + nl) * FD + cc;
            *(float4*)(d32)      = make_float4(o0[0], o0[1], o0[2], o0[3]);
            *(float4*)(d32 + FD) = make_float4(o1[0], o1[1], o1[2], o1[3]);
        }
    }
}

// ---------------------------------------------------------------------------
// Kernel 2: fp32 softmax stats M,L for bt = b*24+23 only (y_last path).
// ---------------------------------------------------------------------------
__global__ __launch_bounds__(256) void k_pass1(const float* __restrict__ q32c,
                                               const float* __restrict__ k32c,
                                               float* __restrict__ Mv,
                                               float* __restrict__ Lv) {
    __shared__ float Qs[32][129];
    __shared__ float Ks[64][129];
    const int tid = threadIdx.x;
    const int b = blockIdx.y;
    const int rowBase = blockIdx.x * 32;
    const float* qb = q32c + (size_t)b * BN * FD;
    const float* kb = k32c + (size_t)b * BN * FD;

    for (int i = 0; i < 4; ++i) {
        int idx = i * 256 + tid;
        int r = idx >> 5, c4 = idx & 31;
        *(float4*)(&Qs[r][c4 * 4]) = *(const float4*)(qb + (size_t)(rowBase + r) * FD + c4 * 4);
    }
    const int tx = tid & 15, ty = tid >> 4;
    const int r0 = ty * 2, r1 = ty * 2 + 1;
    float m[2] = {-1e30f, -1e30f};
    float l[2] = {0.f, 0.f};

    for (int ct = 0; ct < 16; ++ct) {
        __syncthreads();
        for (int i = 0; i < 8; ++i) {
            int idx = i * 256 + tid;
            int r = idx >> 5, c4 = idx & 31;
            *(float4*)(&Ks[r][c4 * 4]) = *(const float4*)(kb + (size_t)(ct * 64 + r) * FD + c4 * 4);
        }
        __syncthreads();
        float e0[4] = {0.f, 0.f, 0.f, 0.f};
        float e1[4] = {0.f, 0.f, 0.f, 0.f};
        for (int kk = 0; kk < FD; ++kk) {
            float a0 = Qs[r0][kk], a1 = Qs[r1][kk];
            float b0 = Ks[tx * 4 + 0][kk];
            float b1 = Ks[tx * 4 + 1][kk];
            float b2 = Ks[tx * 4 + 2][kk];
            float b3 = Ks[tx * 4 + 3][kk];
            e0[0] += a0 * b0; e0[1] += a0 * b1; e0[2] += a0 * b2; e0[3] += a0 * b3;
            e1[0] += a1 * b0; e1[1] += a1 * b1; e1[2] += a1 * b2; e1[3] += a1 * b3;
        }
        float* ep[2] = {e0, e1};
        for (int rr = 0; rr < 2; ++rr) {
            float s0 = ep[rr][0] * SCALE, s1 = ep[rr][1] * SCALE;
            float s2 = ep[rr][2] * SCALE, s3 = ep[rr][3] * SCALE;
            float tm = fmaxf(fmaxf(s0, s1), fmaxf(s2, s3));
            for (int s = 1; s < 16; s <<= 1) tm = fmaxf(tm, __shfl_xor(tm, s, 64));
            float ts = __expf(s0 - tm) + __expf(s1 - tm) + __expf(s2 - tm) + __expf(s3 - tm);
            for (int s = 1; s < 16; s <<= 1) ts += __shfl_xor(ts, s, 64);
            float mn = fmaxf(m[rr], tm);
            l[rr] = l[rr] * __expf(m[rr] - mn) + ts * __expf(tm - mn);
            m[rr] = mn;
        }
    }
    if (tx == 0) {
        Mv[(size_t)b * BN + rowBase + r0] = m[0];
        Lv[(size_t)b * BN + rowBase + r0] = l[0];
        Mv[(size_t)b * BN + rowBase + r1] = m[1];
        Lv[(size_t)b * BN + rowBase + r1] = l[1];
    }
}

// ---------------------------------------------------------------------------
// Kernel 3: fp32 column sums of attn at t=T-1 (y_last path).
// ---------------------------------------------------------------------------
__global__ __launch_bounds__(256) void k_colsum(const float* __restrict__ q32c,
                                                const float* __restrict__ k32c,
                                                const float* __restrict__ Mv,
                                                const float* __restrict__ Lv,
                                                float* __restrict__ cs) {
    __shared__ float Qs[32][129];
    __shared__ float Ks[64][129];
    __shared__ float red[16][68];
    const int tid = threadIdx.x;
    const int b = blockIdx.y;
    const int colBase = blockIdx.x * 64;
    const float* qb = q32c + (size_t)b * BN * FD;
    const float* kb = k32c + (size_t)b * BN * FD;
    const int tx = tid & 15, ty = tid >> 4;
    const int r0 = ty * 2, r1 = ty * 2 + 1;

    for (int i = 0; i < 8; ++i) {
        int idx = i * 256 + tid;
        int r = idx >> 5, c4 = idx & 31;
        *(float4*)(&Ks[r][c4 * 4]) = *(const float4*)(kb + (size_t)(colBase + r) * FD + c4 * 4);
    }

    float acc[4] = {0.f, 0.f, 0.f, 0.f};
    for (int rt = 0; rt < 32; ++rt) {
        __syncthreads();
        for (int i = 0; i < 4; ++i) {
            int idx = i * 256 + tid;
            int r = idx >> 5, c4 = idx & 31;
            *(float4*)(&Qs[r][c4 * 4]) = *(const float4*)(qb + (size_t)(rt * 32 + r) * FD + c4 * 4);
        }
        __syncthreads();
        float e0[4] = {0.f, 0.f, 0.f, 0.f};
        float e1[4] = {0.f, 0.f, 0.f, 0.f};
        for (int kk = 0; kk < FD; ++kk) {
            float a0 = Qs[r0][kk], a1 = Qs[r1][kk];
            float b0 = Ks[tx * 4 + 0][kk];
            float b1 = Ks[tx * 4 + 1][kk];
            float b2 = Ks[tx * 4 + 2][kk];
            float b3 = Ks[tx * 4 + 3][kk];
            e0[0] += a0 * b0; e0[1] += a0 * b1; e0[2] += a0 * b2; e0[3] += a0 * b3;
            e1[0] += a1 * b0; e1[1] += a1 * b1; e1[2] += a1 * b2; e1[3] += a1 * b3;
        }
        int n0 = rt * 32 + r0, n1 = rt * 32 + r1;
        float m0 = Mv[(size_t)b * BN + n0], il0 = 1.0f / Lv[(size_t)b * BN + n0];
        float m1 = Mv[(size_t)b * BN + n1], il1 = 1.0f / Lv[(size_t)b * BN + n1];
        for (int j = 0; j < 4; ++j) {
            acc[j] += __expf(e0[j] * SCALE - m0) * il0;
            acc[j] += __expf(e1[j] * SCALE - m1) * il1;
        }
    }
    for (int j = 0; j < 4; ++j) red[ty][tx * 4 + j] = acc[j];
    __syncthreads();
    if (tid < 64) {
        float s = 0.f;
        for (int i = 0; i < 16; ++i) s += red[i][tid];
        cs[(size_t)b * BN + colBase + tid] = s;
    }
}

// ---------------------------------------------------------------------------
// Kernel 4: index of 3rd-smallest column sum (top_k tie-break: lower index).
// ---------------------------------------------------------------------------
__global__ void k_top3(const float* __restrict__ cs, int* __restrict__ ylast) {
    __shared__ float sv[192];
    __shared__ int si[192];
    const int b = blockIdx.x;
    const int t = threadIdx.x;
    float bv[3] = {1e30f, 1e30f, 1e30f};
    int bi[3] = {0x7fffffff, 0x7fffffff, 0x7fffffff};
    for (int i = 0; i < 16; ++i) {
        int idx = t * 16 + i;
        float vv = cs[(size_t)b * BN + idx];
        if (vv < bv[0]) {
            bv[2] = bv[1]; bi[2] = bi[1];
            bv[1] = bv[0]; bi[1] = bi[0];
            bv[0] = vv;    bi[0] = idx;
        } else if (vv < bv[1]) {
            bv[2] = bv[1]; bi[2] = bi[1];
            bv[1] = vv;    bi[1] = idx;
        } else if (vv < bv[2]) {
            bv[2] = vv;    bi[2] = idx;
        }
    }
    for (int j = 0; j < 3; ++j) { sv[t * 3 + j] = bv[j]; si[t * 3 + j] = bi[j]; }
    __syncthreads();
    if (t == 0) {
        float fv[3] = {1e30f, 1e30f, 1e30f};
        int fi[3] = {0x7fffffff, 0x7fffffff, 0x7fffffff};
        for (int c = 0; c < 192; ++c) {
            float vv = sv[c]; int ii = si[c];
            if (vv < fv[0] || (vv == fv[0] && ii < fi[0])) {
                fv[2] = fv[1]; fi[2] = fi[1];
                fv[1] = fv[0]; fi[1] = fi[0];
                fv[0] = vv;    fi[0] = ii;
            } else if (vv < fv[1] || (vv == fv[1] && ii < fi[1])) {
                fv[2] = fv[1]; fi[2] = fi[1];
                fv[1] = vv;    fi[1] = ii;
            } else if (vv < fv[2] || (vv == fv[2] && ii < fi[2])) {
                fv[2] = vv;    fi[2] = ii;
            }
        }
        ylast[b] = fi[2];
    }
}

// ---------------------------------------------------------------------------
// Kernel 5: mixup of row y for t < FRONT_T. Mean from fp32 v; exact integer
// result written into bf16 transposed v (0..255 exact in bf16).
// ---------------------------------------------------------------------------
__global__ void k_mixup(const float* __restrict__ v32f,
                        unsigned short* __restrict__ vtb,
                        const int* __restrict__ ylast) {
    const int b = blockIdx.y, t = blockIdx.x, f = threadIdx.x;
    const int y = ylast[b];
    const int ys = max(y - 1, 0), ye = min(y + 2, BN);
    const float* vb = v32f + (size_t)(b * FRONT_T + t) * BN * FD + f;
    float s = 0.f;
    for (int r = ys; r < ye; ++r) s += vb[(size_t)r * FD];
    s /= (float)(ye - ys);
    int ti = (int)s;                              // trunc toward zero
    unsigned u = ((unsigned)ti) & 0xFFu;          // wrap mod 256 (numpy/x86)
    vtb[((size_t)(b * TT + t) * FD + f) * BN + y] = f2bf((float)u);
}

// ---------------------------------------------------------------------------
// Kernel 6: flash attention core ONLY (bf16 MFMA QK^T + online softmax +
// bf16 MFMA P.V). Writes normalized value_i to global fp32 (C-layout rows).
// 64 Q-rows/block, 4 waves x 16 rows.
// ---------------------------------------------------------------------------
__global__ __launch_bounds__(256, 2) void k_flash(
    const unsigned short* __restrict__ qb, const unsigned short* __restrict__ kb,
    const unsigned short* __restrict__ vtb, float* __restrict__ vi)
{
    __shared__ __attribute__((aligned(16))) unsigned short Qs[64 * 136];
    __shared__ __attribute__((aligned(16))) unsigned short Ks[64 * 136];
    __shared__ __attribute__((aligned(16))) unsigned short Vts[128 * 72];
    __shared__ __attribute__((aligned(16))) unsigned short Ps[4][16 * 72];
    const int tid = threadIdx.x;
    const int bt = blockIdx.y;
    const int rowBase = blockIdx.x * 64;
    const int lane = tid & 63, wave = tid >> 6;
    const int lx = lane & 15, quad = lane >> 4;

    const unsigned short* qg = qb + ((size_t)bt * BN + rowBase) * FD;
    for (int i = 0; i < 4; ++i) {
        int idx = i * 256 + tid, r = idx >> 4, c8 = idx & 15;
        *(int4*)(&Qs[r * 136 + c8 * 8]) = *(const int4*)(qg + r * FD + c8 * 8);
    }
    __syncthreads();

    s8v aq[4];
    for (int t4 = 0; t4 < 4; ++t4)
        aq[t4] = *(const s8v*)(&Qs[(wave * 16 + lx) * 136 + t4 * 32 + quad * 8]);

    f4v O[8];
    for (int gg = 0; gg < 8; ++gg) O[gg] = (f4v){0.f, 0.f, 0.f, 0.f};
    float mrow[4] = {-1e30f, -1e30f, -1e30f, -1e30f};
    float lrow[4] = {0.f, 0.f, 0.f, 0.f};

    const unsigned short* kgbase = kb + (size_t)bt * BN * FD;
    const unsigned short* vgbase = vtb + (size_t)bt * FD * BN;

    for (int ct = 0; ct < 16; ++ct) {
        __syncthreads();
        const unsigned short* kg = kgbase + (size_t)ct * 64 * FD;
        for (int i = 0; i < 4; ++i) {
            int idx = i * 256 + tid, r = idx >> 4, c8 = idx & 15;
            *(int4*)(&Ks[r * 136 + c8 * 8]) = *(const int4*)(kg + r * FD + c8 * 8);
        }
        for (int i = 0; i < 4; ++i) {
            int idx = i * 256 + tid, r = idx >> 3, c8 = idx & 7;
            *(int4*)(&Vts[r * 72 + c8 * 8]) = *(const int4*)(vgbase + (size_t)r * BN + ct * 64 + c8 * 8);
        }
        __syncthreads();

        f4v e[4];
        for (int n4 = 0; n4 < 4; ++n4) {
            f4v acc = (f4v){0.f, 0.f, 0.f, 0.f};
            for (int t4 = 0; t4 < 4; ++t4) {
                s8v bk = *(const s8v*)(&Ks[(n4 * 16 + lx) * 136 + t4 * 32 + quad * 8]);
                acc = __builtin_amdgcn_mfma_f32_16x16x32_bf16(aq[t4], bk, acc, 0, 0, 0);
            }
            for (int r = 0; r < 4; ++r) acc[r] *= SCALE;
            e[n4] = acc;
        }
        for (int r = 0; r < 4; ++r) {
            float tm = fmaxf(fmaxf(e[0][r], e[1][r]), fmaxf(e[2][r], e[3][r]));
            for (int s = 1; s < 16; s <<= 1) tm = fmaxf(tm, __shfl_xor(tm, s, 64));
            float mn = fmaxf(mrow[r], tm);
            float alpha = __expf(mrow[r] - mn);
            mrow[r] = mn;
            float ps = 0.f;
            for (int n4 = 0; n4 < 4; ++n4) {
                float p = __expf(e[n4][r] - mn);
                e[n4][r] = p;
                ps += p;
            }
            for (int s = 1; s < 16; s <<= 1) ps += __shfl_xor(ps, s, 64);
            lrow[r] = lrow[r] * alpha + ps;
            for (int gg = 0; gg < 8; ++gg) O[gg][r] *= alpha;
        }
        // P: C-layout -> A-layout via per-wave LDS slice (same-wave DS is in-order)
        for (int n4 = 0; n4 < 4; ++n4)
            for (int r = 0; r < 4; ++r)
                Ps[wave][(quad * 4 + r) * 72 + n4 * 16 + lx] = f2bf(e[n4][r]);
        for (int k2 = 0; k2 < 2; ++k2) {
            s8v ap = *(const s8v*)(&Ps[wave][lx * 72 + k2 * 32 + quad * 8]);
            for (int gg = 0; gg < 8; ++gg) {
                s8v bv = *(const s8v*)(&Vts[(gg * 16 + lx) * 72 + k2 * 32 + quad * 8]);
                O[gg] = __builtin_amdgcn_mfma_f32_16x16x32_bf16(ap, bv, O[gg], 0, 0, 0);
            }
        }
    }
    // normalize and write value_i (fp32) to global, C-layout rows
    const int row0 = rowBase + wave * 16 + quad * 4;
    for (int r = 0; r < 4; ++r) {
        float inv = 1.0f / lrow[r];
        for (int gg = 0; gg < 8; ++gg)
            vi[((size_t)bt * BN + row0 + r) * FD + gg * 16 + lx] = O[gg][r] * inv;
    }
}

// ---------------------------------------------------------------------------
// Kernel 7: FF1+gelu+FF2+residual+LayerNorm -- round-1 VERBATIM fp32 code,
// with the attention result loaded from vi instead of computed in-kernel.
// ---------------------------------------------------------------------------
__global__ __launch_bounds__(256) void k_ffn(const float* __restrict__ vi,
                                             const float* __restrict__ x,
                                             const float* __restrict__ W1,
                                             const float* __restrict__ b1,
                                             const float* __restrict__ W2,
                                             const float* __restrict__ b2,
                                             const float* __restrict__ g,
                                             const float* __restrict__ lb,
                                             float* __restrict__ out) {
    __shared__ float Qs[32][132];
    __shared__ float KVs[64][132];
    const int tid = threadIdx.x;
    const int bt = blockIdx.y;
    const int rowBase = blockIdx.x * 32;
    const int tx = tid & 15, ty = tid >> 4;
    const int r0 = ty * 2, r1 = ty * 2 + 1;

    const float* vb = vi + ((size_t)bt * BN + rowBase) * FD;
    for (int i = 0; i < 4; ++i) {
        int idx = i * 256 + tid;
        int r = idx >> 5, c4 = idx & 31;
        *(float4*)(&Qs[r][c4 * 4]) = *(const float4*)(vb + (size_t)r * FD + c4 * 4);
    }

    // FF1: h = gelu(u @ W1^T + b1). Output f(j) = tx+16*j; chunk 0 = j<4.
    float h0[8], h1[8];
    {
        float t0[8] = {}, t1[8] = {};
        for (int ch = 0; ch < 2; ++ch) {
            __syncthreads();
            for (int i = 0; i < 8; ++i) {
                int idx = i * 256 + tid;
                int r = idx >> 5, c4 = idx & 31;
                *(float4*)(&KVs[r][c4 * 4]) = *(const float4*)(W1 + (size_t)(ch * 64 + r) * FD + c4 * 4);
            }
            __syncthreads();
            for (int kk = 0; kk < FD; ++kk) {
                float u0 = Qs[r0][kk], u1 = Qs[r1][kk];
                for (int jj = 0; jj < 4; ++jj) {
                    int j = jj + 4 * ch;
                    float w = KVs[tx + 16 * jj][kk];
                    t0[j] += u0 * w;
                    t1[j] += u1 * w;
                }
            }
        }
        for (int j = 0; j < 8; ++j) {
            int f = tx + 16 * j;
            float bj = b1[f];
            float z0 = t0[j] + bj, z1 = t1[j] + bj;
            h0[j] = 0.5f * z0 * (1.0f + erff(z0 * GELU_K));
            h1[j] = 0.5f * z1 * (1.0f + erff(z1 * GELU_K));
        }
    }
    __syncthreads();
    for (int j = 0; j < 8; ++j) { Qs[r0][tx + 16 * j] = h0[j]; Qs[r1][tx + 16 * j] = h1[j]; }
    __syncthreads();

    // FF2: z = h @ W2^T + b2
    float z0[8], z1[8];
    {
        float t0[8] = {}, t1[8] = {};
        for (int ch = 0; ch < 2; ++ch) {
            __syncthreads();
            for (int i = 0; i < 8; ++i) {
                int idx = i * 256 + tid;
                int r = idx >> 5, c4 = idx & 31;
                *(float4*)(&KVs[r][c4 * 4]) = *(const float4*)(W2 + (size_t)(ch * 64 + r) * FD + c4 * 4);
            }
            __syncthreads();
            for (int kk = 0; kk < FD; ++kk) {
                float u0 = Qs[r0][kk], u1 = Qs[r1][kk];
                for (int jj = 0; jj < 4; ++jj) {
                    int j = jj + 4 * ch;
                    float w = KVs[tx + 16 * jj][kk];
                    t0[j] += u0 * w;
                    t1[j] += u1 * w;
                }
            }
        }
        for (int j = 0; j < 8; ++j) {
            int f = tx + 16 * j;
            float bj = b2[f];
            z0[j] = t0[j] + bj;
            z1[j] = t1[j] + bj;
        }
    }

    // residual + LayerNorm over F
    const float* xb = x + ((size_t)bt * BN + rowBase) * FD;
    float res0[8], res1[8];
    float s0 = 0.f, s1 = 0.f;
    for (int j = 0; j < 8; ++j) {
        int f = tx + 16 * j;
        res0[j] = z0[j] + xb[(size_t)r0 * FD + f];
        res1[j] = z1[j] + xb[(size_t)r1 * FD + f];
        s0 += res0[j];
        s1 += res1[j];
    }
    for (int s = 1; s < 16; s <<= 1) { s0 += __shfl_xor(s0, s, 64); s1 += __shfl_xor(s1, s, 64); }
    const float mu0 = s0 * (1.0f / FD), mu1 = s1 * (1.0f / FD);
    float q0 = 0.f, q1 = 0.f;
    for (int j = 0; j < 8; ++j) {
        float d0 = res0[j] - mu0, d1 = res1[j] - mu1;
        q0 += d0 * d0;
        q1 += d1 * d1;
    }
    for (int s = 1; s < 16; s <<= 1) { q0 += __shfl_xor(q0, s, 64); q1 += __shfl_xor(q1, s, 64); }
    const float rs0 = rsqrtf(q0 * (1.0f / FD) + 1e-5f);
    const float rs1 = rsqrtf(q1 * (1.0f / FD) + 1e-5f);
    float* ob = out + ((size_t)bt * BN + rowBase) * FD;
    for (int j = 0; j < 8; ++j) {
        int f = tx + 16 * j;
        float gf = g[f], bf = lb[f];
        ob[(size_t)r0 * FD + f] = (res0[j] - mu0) * rs0 * gf + bf;
        ob[(size_t)r1 * FD + f] = (res1[j] - mu1) * rs1 * gf + bf;
    }
}

// ---------------------------------------------------------------------------
extern "C" void kernel_launch(void* const* d_in, const int* in_sizes, int n_in,
                              void* d_out, int out_size, void* d_ws, size_t ws_size,
                              hipStream_t stream) {
    const float* x     = (const float*)d_in[0];
    const float* W_xff = (const float*)d_in[1];
    const float* b_xff = (const float*)d_in[2];
    const float* W_ff1 = (const float*)d_in[3];
    const float* b_ff1 = (const float*)d_in[4];
    const float* W_ff2 = (const float*)d_in[5];
    const float* b_ff2 = (const float*)d_in[6];
    const float* ln_g  = (const float*)d_in[7];
    const float* ln_b  = (const float*)d_in[8];
    float* out = (float*)d_out;

    char* w = (char*)d_ws;
    unsigned short* qb16 = (unsigned short*)w;  w += (size_t)BTN * FD * 2;
    unsigned short* kb16 = (unsigned short*)w;  w += (size_t)BTN * FD * 2;
    unsigned short* vtb  = (unsigned short*)w;  w += (size_t)BTN * FD * 2;
    // vi aliases the region holding v32f/q32c/k32c/stats -- all of those are
    // fully consumed (by pass1/colsum/top3/mixup) before k_flash writes vi.
    char* alias = w;
    float* vi   = (float*)alias;                // BTN*FD*4 = 50.3 MB
    float* v32f = (float*)alias;                alias += (size_t)BB * FRONT_T * BN * FD * 4;
    float* q32c = (float*)alias;                alias += (size_t)BB * BN * FD * 4;
    float* k32c = (float*)alias;                alias += (size_t)BB * BN * FD * 4;
    float* Mv   = (float*)alias;                alias += (size_t)BB * BN * 4;
    float* Lv   = (float*)alias;                alias += (size_t)BB * BN * 4;
    float* cs   = (float*)alias;                alias += (size_t)BB * BN * 4;
    int* ylast  = (int*)alias;

    k_qkv   <<<dim3(BTN / 32, 6), 256, 0, stream>>>(x, W_xff, b_xff, qb16, kb16, vtb,
                                                    q32c, k32c, v32f);
    k_pass1 <<<dim3(32, BB),      256, 0, stream>>>(q32c, k32c, Mv, Lv);
    k_colsum<<<dim3(16, BB),      256, 0, stream>>>(q32c, k32c, Mv, Lv, cs);
    k_top3  <<<dim3(BB),           64, 0, stream>>>(cs, ylast);
    k_mixup <<<dim3(FRONT_T, BB), 128, 0, stream>>>(v32f, vtb, ylast);
    k_flash <<<dim3(16, BT),      256, 0, stream>>>(qb16, kb16, vtb, vi);
    k_ffn   <<<dim3(32, BT),      256, 0, stream>>>(vi, x, W_ff1, b_ff1, W_ff2, b_ff2,
                                                    ln_g, ln_b, out);
}

// Round 5
// 694.779 us; speedup vs baseline: 3.5939x; 1.3608x over previous
//
#include <hip/hip_runtime.h>
#include <math.h>

#define BB 4
#define TT 24
#define BN 1024
#define FD 128
#define BT (BB*TT)
#define BTN (BT*BN)
#define FRONT_T 12
#define SCALE 0.08838834764831845f   // 1/sqrt(128)
#define GELU_K 0.7071067811865476f   // 1/sqrt(2)

typedef __attribute__((ext_vector_type(8))) short s8v;   // 8 bf16 (4 VGPRs)
typedef __attribute__((ext_vector_type(4))) float f4v;   // 4 fp32 acc

static __device__ __forceinline__ unsigned short f2bf(float f) {
    union { float f; unsigned u; } c; c.f = f;
    unsigned u = c.u + 0x7FFFu + ((c.u >> 16) & 1u);   // RNE
    return (unsigned short)(u >> 16);
}

// ---------------------------------------------------------------------------
// Conversions: x -> bf16 (bulk GEMM input), W_xff -> bf16.
// ---------------------------------------------------------------------------
__global__ __launch_bounds__(256) void k_convx(const float* __restrict__ x,
                                               unsigned short* __restrict__ xb) {
    size_t i = ((size_t)blockIdx.x * 256 + threadIdx.x) * 4;
    float4 v = *(const float4*)(x + i);
    ushort4 h = {f2bf(v.x), f2bf(v.y), f2bf(v.z), f2bf(v.w)};
    *(ushort4*)(xb + i) = h;
}

__global__ void k_convw(const float* __restrict__ W, unsigned short* __restrict__ wb, int n) {
    int i = blockIdx.x * 256 + threadIdx.x;
    if (i < n) wb[i] = f2bf(W[i]);
}

// ---------------------------------------------------------------------------
// Bulk qkv GEMM in bf16 MFMA. Tile: 64 rows x 64 cols, K=128.
// A/B frag patterns + C-layout identical to the validated k_flash kernel.
// Epilogue repacks C via LDS: q/k row-major int4 stores; v transposed
// [bt][f][n] with n-contiguous int4 stores.
// ---------------------------------------------------------------------------
__global__ __launch_bounds__(256, 2) void k_qkv_mfma(
    const unsigned short* __restrict__ xb, const unsigned short* __restrict__ wb,
    const float* __restrict__ bias,
    unsigned short* __restrict__ qb16, unsigned short* __restrict__ kb16,
    unsigned short* __restrict__ vtb)
{
    __shared__ __attribute__((aligned(16))) unsigned short Xs[64 * 136];
    __shared__ __attribute__((aligned(16))) unsigned short Ws[64 * 136];
    __shared__ __attribute__((aligned(16))) unsigned short Cs[64 * 72];
    const int tid = threadIdx.x;
    const int rowBase = blockIdx.x * 64;
    const int colBase = blockIdx.y * 64;
    const int lane = tid & 63, wave = tid >> 6;
    const int lx = lane & 15, quad = lane >> 4;

    for (int i = 0; i < 4; ++i) {
        int idx = i * 256 + tid, r = idx >> 4, c8 = idx & 15;
        *(int4*)(&Xs[r * 136 + c8 * 8]) = *(const int4*)(xb + (size_t)(rowBase + r) * FD + c8 * 8);
    }
    for (int i = 0; i < 4; ++i) {
        int idx = i * 256 + tid, r = idx >> 4, c8 = idx & 15;
        *(int4*)(&Ws[r * 136 + c8 * 8]) = *(const int4*)(wb + (size_t)(colBase + r) * FD + c8 * 8);
    }
    __syncthreads();

    f4v acc[4];
    for (int gg = 0; gg < 4; ++gg) acc[gg] = (f4v){0.f, 0.f, 0.f, 0.f};
    for (int t4 = 0; t4 < 4; ++t4) {
        s8v a = *(const s8v*)(&Xs[(wave * 16 + lx) * 136 + t4 * 32 + quad * 8]);
        for (int gg = 0; gg < 4; ++gg) {
            s8v b = *(const s8v*)(&Ws[(gg * 16 + lx) * 136 + t4 * 32 + quad * 8]);
            acc[gg] = __builtin_amdgcn_mfma_f32_16x16x32_bf16(a, b, acc[gg], 0, 0, 0);
        }
    }

    const int n0 = wave * 16 + quad * 4;          // C rows (n_local)
    if (colBase < 2 * FD) {
        for (int gg = 0; gg < 4; ++gg) {
            float bb = bias[colBase + gg * 16 + lx];
            for (int r = 0; r < 4; ++r)
                Cs[(n0 + r) * 72 + gg * 16 + lx] = f2bf(acc[gg][r] + bb);
        }
        __syncthreads();
        unsigned short* dst = (colBase < FD) ? qb16 : kb16;
        const int cc0 = colBase & (FD - 1);
        for (int i = 0; i < 2; ++i) {
            int idx = i * 256 + tid, r = idx >> 3, c8 = idx & 7;
            *(int4*)(dst + (size_t)(rowBase + r) * FD + cc0 + c8 * 8) =
                *(const int4*)(&Cs[r * 72 + c8 * 8]);
        }
    } else {
        for (int gg = 0; gg < 4; ++gg) {
            float bb = bias[colBase + gg * 16 + lx];
            for (int r = 0; r < 4; ++r)
                Cs[(gg * 16 + lx) * 72 + n0 + r] = f2bf(acc[gg][r] + bb);
        }
        __syncthreads();
        const int bt = rowBase >> 10, nBase = rowBase & 1023, cc0 = colBase - 2 * FD;
        for (int i = 0; i < 2; ++i) {
            int idx = i * 256 + tid, f = idx >> 3, c8 = idx & 7;
            *(int4*)(vtb + ((size_t)bt * FD + cc0 + f) * BN + nBase + c8 * 8) =
                *(const int4*)(&Cs[f * 72 + c8 * 8]);
        }
    }
}

// ---------------------------------------------------------------------------
// Exact fp32 GEMM (round-1 verbatim arithmetic) for the bt%24==23 slices
// only -> q32c/k32c bitwise identical to the round-1/4 y_last path.
// ---------------------------------------------------------------------------
__global__ __launch_bounds__(256) void k_qkv32(const float* __restrict__ x,
                                               const float* __restrict__ W,
                                               const float* __restrict__ bias,
                                               float* __restrict__ q32c,
                                               float* __restrict__ k32c) {
    __shared__ float Xs[32][129];
    __shared__ float Ws[64][129];
    const int tid = threadIdx.x;
    const int b = blockIdx.x >> 5;
    const int rt = blockIdx.x & 31;
    const int xrow0 = (b * TT + (TT - 1)) * BN + rt * 32;
    const int colBase = blockIdx.y * 64;      // 0..192 (q,k cols only)

    for (int i = 0; i < 4; ++i) {
        int idx = i * 256 + tid;
        int r = idx >> 5, c4 = idx & 31;
        *(float4*)(&Xs[r][c4 * 4]) = *(const float4*)(x + (size_t)(xrow0 + r) * FD + c4 * 4);
    }
    for (int i = 0; i < 8; ++i) {
        int idx = i * 256 + tid;
        int r = idx >> 5, c4 = idx & 31;
        *(float4*)(&Ws[r][c4 * 4]) = *(const float4*)(W + (size_t)(colBase + r) * FD + c4 * 4);
    }
    __syncthreads();

    const int tx = tid & 15, ty = tid >> 4;
    const int r0 = ty * 2, r1 = ty * 2 + 1;
    float acc0[4] = {0.f, 0.f, 0.f, 0.f};
    float acc1[4] = {0.f, 0.f, 0.f, 0.f};
    for (int kk = 0; kk < FD; ++kk) {
        float a0 = Xs[r0][kk], a1 = Xs[r1][kk];
        float b0 = Ws[tx * 4 + 0][kk];
        float b1 = Ws[tx * 4 + 1][kk];
        float b2 = Ws[tx * 4 + 2][kk];
        float b3 = Ws[tx * 4 + 3][kk];
        acc0[0] += a0 * b0; acc0[1] += a0 * b1; acc0[2] += a0 * b2; acc0[3] += a0 * b3;
        acc1[0] += a1 * b0; acc1[1] += a1 * b1; acc1[2] += a1 * b2; acc1[3] += a1 * b3;
    }
    const int c = colBase + tx * 4;
    float4 bia = *(const float4*)(bias + c);
    float* dst = (c < FD) ? q32c : k32c;
    int cc = (c < FD) ? c : c - FD;
    size_t base = ((size_t)b * BN + rt * 32 + r0) * FD + cc;
    *(float4*)(dst + base)      = make_float4(acc0[0] + bia.x, acc0[1] + bia.y, acc0[2] + bia.z, acc0[3] + bia.w);
    *(float4*)(dst + base + FD) = make_float4(acc1[0] + bia.x, acc1[1] + bia.y, acc1[2] + bia.z, acc1[3] + bia.w);
}

// ---------------------------------------------------------------------------
// Kernel 2: fp32 softmax stats M,L for bt = b*24+23 only (y_last path).
// ---------------------------------------------------------------------------
__global__ __launch_bounds__(256) void k_pass1(const float* __restrict__ q32c,
                                               const float* __restrict__ k32c,
                                               float* __restrict__ Mv,
                                               float* __restrict__ Lv) {
    __shared__ float Qs[32][129];
    __shared__ float Ks[64][129];
    const int tid = threadIdx.x;
    const int b = blockIdx.y;
    const int rowBase = blockIdx.x * 32;
    const float* qb = q32c + (size_t)b * BN * FD;
    const float* kb = k32c + (size_t)b * BN * FD;

    for (int i = 0; i < 4; ++i) {
        int idx = i * 256 + tid;
        int r = idx >> 5, c4 = idx & 31;
        *(float4*)(&Qs[r][c4 * 4]) = *(const float4*)(qb + (size_t)(rowBase + r) * FD + c4 * 4);
    }
    const int tx = tid & 15, ty = tid >> 4;
    const int r0 = ty * 2, r1 = ty * 2 + 1;
    float m[2] = {-1e30f, -1e30f};
    float l[2] = {0.f, 0.f};

    for (int ct = 0; ct < 16; ++ct) {
        __syncthreads();
        for (int i = 0; i < 8; ++i) {
            int idx = i * 256 + tid;
            int r = idx >> 5, c4 = idx & 31;
            *(float4*)(&Ks[r][c4 * 4]) = *(const float4*)(kb + (size_t)(ct * 64 + r) * FD + c4 * 4);
        }
        __syncthreads();
        float e0[4] = {0.f, 0.f, 0.f, 0.f};
        float e1[4] = {0.f, 0.f, 0.f, 0.f};
        for (int kk = 0; kk < FD; ++kk) {
            float a0 = Qs[r0][kk], a1 = Qs[r1][kk];
            float b0 = Ks[tx * 4 + 0][kk];
            float b1 = Ks[tx * 4 + 1][kk];
            float b2 = Ks[tx * 4 + 2][kk];
            float b3 = Ks[tx * 4 + 3][kk];
            e0[0] += a0 * b0; e0[1] += a0 * b1; e0[2] += a0 * b2; e0[3] += a0 * b3;
            e1[0] += a1 * b0; e1[1] += a1 * b1; e1[2] += a1 * b2; e1[3] += a1 * b3;
        }
        float* ep[2] = {e0, e1};
        for (int rr = 0; rr < 2; ++rr) {
            float s0 = ep[rr][0] * SCALE, s1 = ep[rr][1] * SCALE;
            float s2 = ep[rr][2] * SCALE, s3 = ep[rr][3] * SCALE;
            float tm = fmaxf(fmaxf(s0, s1), fmaxf(s2, s3));
            for (int s = 1; s < 16; s <<= 1) tm = fmaxf(tm, __shfl_xor(tm, s, 64));
            float ts = __expf(s0 - tm) + __expf(s1 - tm) + __expf(s2 - tm) + __expf(s3 - tm);
            for (int s = 1; s < 16; s <<= 1) ts += __shfl_xor(ts, s, 64);
            float mn = fmaxf(m[rr], tm);
            l[rr] = l[rr] * __expf(m[rr] - mn) + ts * __expf(tm - mn);
            m[rr] = mn;
        }
    }
    if (tx == 0) {
        Mv[(size_t)b * BN + rowBase + r0] = m[0];
        Lv[(size_t)b * BN + rowBase + r0] = l[0];
        Mv[(size_t)b * BN + rowBase + r1] = m[1];
        Lv[(size_t)b * BN + rowBase + r1] = l[1];
    }
}

// ---------------------------------------------------------------------------
// Kernel 3: fp32 column sums of attn at t=T-1 (y_last path).
// ---------------------------------------------------------------------------
__global__ __launch_bounds__(256) void k_colsum(const float* __restrict__ q32c,
                                                const float* __restrict__ k32c,
                                                const float* __restrict__ Mv,
                                                const float* __restrict__ Lv,
                                                float* __restrict__ cs) {
    __shared__ float Qs[32][129];
    __shared__ float Ks[64][129];
    __shared__ float red[16][68];
    const int tid = threadIdx.x;
    const int b = blockIdx.y;
    const int colBase = blockIdx.x * 64;
    const float* qb = q32c + (size_t)b * BN * FD;
    const float* kb = k32c + (size_t)b * BN * FD;
    const int tx = tid & 15, ty = tid >> 4;
    const int r0 = ty * 2, r1 = ty * 2 + 1;

    for (int i = 0; i < 8; ++i) {
        int idx = i * 256 + tid;
        int r = idx >> 5, c4 = idx & 31;
        *(float4*)(&Ks[r][c4 * 4]) = *(const float4*)(kb + (size_t)(colBase + r) * FD + c4 * 4);
    }

    float acc[4] = {0.f, 0.f, 0.f, 0.f};
    for (int rt = 0; rt < 32; ++rt) {
        __syncthreads();
        for (int i = 0; i < 4; ++i) {
            int idx = i * 256 + tid;
            int r = idx >> 5, c4 = idx & 31;
            *(float4*)(&Qs[r][c4 * 4]) = *(const float4*)(qb + (size_t)(rt * 32 + r) * FD + c4 * 4);
        }
        __syncthreads();
        float e0[4] = {0.f, 0.f, 0.f, 0.f};
        float e1[4] = {0.f, 0.f, 0.f, 0.f};
        for (int kk = 0; kk < FD; ++kk) {
            float a0 = Qs[r0][kk], a1 = Qs[r1][kk];
            float b0 = Ks[tx * 4 + 0][kk];
            float b1 = Ks[tx * 4 + 1][kk];
            float b2 = Ks[tx * 4 + 2][kk];
            float b3 = Ks[tx * 4 + 3][kk];
            e0[0] += a0 * b0; e0[1] += a0 * b1; e0[2] += a0 * b2; e0[3] += a0 * b3;
            e1[0] += a1 * b0; e1[1] += a1 * b1; e1[2] += a1 * b2; e1[3] += a1 * b3;
        }
        int n0 = rt * 32 + r0, n1 = rt * 32 + r1;
        float m0 = Mv[(size_t)b * BN + n0], il0 = 1.0f / Lv[(size_t)b * BN + n0];
        float m1 = Mv[(size_t)b * BN + n1], il1 = 1.0f / Lv[(size_t)b * BN + n1];
        for (int j = 0; j < 4; ++j) {
            acc[j] += __expf(e0[j] * SCALE - m0) * il0;
            acc[j] += __expf(e1[j] * SCALE - m1) * il1;
        }
    }
    for (int j = 0; j < 4; ++j) red[ty][tx * 4 + j] = acc[j];
    __syncthreads();
    if (tid < 64) {
        float s = 0.f;
        for (int i = 0; i < 16; ++i) s += red[i][tid];
        cs[(size_t)b * BN + colBase + tid] = s;
    }
}

// ---------------------------------------------------------------------------
// Kernel 4: index of 3rd-smallest column sum (top_k tie-break: lower index).
// ---------------------------------------------------------------------------
__global__ void k_top3(const float* __restrict__ cs, int* __restrict__ ylast) {
    __shared__ float sv[192];
    __shared__ int si[192];
    const int b = blockIdx.x;
    const int t = threadIdx.x;
    float bv[3] = {1e30f, 1e30f, 1e30f};
    int bi[3] = {0x7fffffff, 0x7fffffff, 0x7fffffff};
    for (int i = 0; i < 16; ++i) {
        int idx = t * 16 + i;
        float vv = cs[(size_t)b * BN + idx];
        if (vv < bv[0]) {
            bv[2] = bv[1]; bi[2] = bi[1];
            bv[1] = bv[0]; bi[1] = bi[0];
            bv[0] = vv;    bi[0] = idx;
        } else if (vv < bv[1]) {
            bv[2] = bv[1]; bi[2] = bi[1];
            bv[1] = vv;    bi[1] = idx;
        } else if (vv < bv[2]) {
            bv[2] = vv;    bi[2] = idx;
        }
    }
    for (int j = 0; j < 3; ++j) { sv[t * 3 + j] = bv[j]; si[t * 3 + j] = bi[j]; }
    __syncthreads();
    if (t == 0) {
        float fv[3] = {1e30f, 1e30f, 1e30f};
        int fi[3] = {0x7fffffff, 0x7fffffff, 0x7fffffff};
        for (int c = 0; c < 192; ++c) {
            float vv = sv[c]; int ii = si[c];
            if (vv < fv[0] || (vv == fv[0] && ii < fi[0])) {
                fv[2] = fv[1]; fi[2] = fi[1];
                fv[1] = fv[0]; fi[1] = fi[0];
                fv[0] = vv;    fi[0] = ii;
            } else if (vv < fv[1] || (vv == fv[1] && ii < fi[1])) {
                fv[2] = fv[1]; fi[2] = fi[1];
                fv[1] = vv;    fi[1] = ii;
            } else if (vv < fv[2] || (vv == fv[2] && ii < fi[2])) {
                fv[2] = vv;    fi[2] = ii;
            }
        }
        ylast[b] = fi[2];
    }
}

// ---------------------------------------------------------------------------
// Kernel 5: mixup. Recomputes the 3 window v-rows in fp32 directly from
// x/W_xff with round-1's exact FMA order (no reassociation w/o fast-math),
// so the uint8-wrap cast input is bitwise identical to the passing rounds.
// ---------------------------------------------------------------------------
__global__ void k_mixup(const float* __restrict__ x, const float* __restrict__ W,
                        const float* __restrict__ bias,
                        unsigned short* __restrict__ vtb,
                        const int* __restrict__ ylast) {
    const int b = blockIdx.y, t = blockIdx.x, f = threadIdx.x;
    const int y = ylast[b];
    const int ys = max(y - 1, 0), ye = min(y + 2, BN);
    const float* wrow = W + (size_t)(2 * FD + f) * FD;
    const float bia = bias[2 * FD + f];
    float s = 0.f;
    for (int r = ys; r < ye; ++r) {
        const float* xrow = x + ((size_t)(b * TT + t) * BN + r) * FD;
        float acc = 0.f;
        for (int kk = 0; kk < FD; ++kk) acc += xrow[kk] * wrow[kk];
        s += acc + bia;
    }
    s /= (float)(ye - ys);
    int ti = (int)s;                              // trunc toward zero
    unsigned u = ((unsigned)ti) & 0xFFu;          // wrap mod 256 (numpy/x86)
    vtb[((size_t)(b * TT + t) * FD + f) * BN + y] = f2bf((float)u);
}

// ---------------------------------------------------------------------------
// Kernel 6: flash attention core (bf16 MFMA QK^T + online softmax + P.V).
// Writes normalized value_i to global fp32. (Validated in round 4.)
// ---------------------------------------------------------------------------
__global__ __launch_bounds__(256, 2) void k_flash(
    const unsigned short* __restrict__ qb, const unsigned short* __restrict__ kb,
    const unsigned short* __restrict__ vtb, float* __restrict__ vi)
{
    __shared__ __attribute__((aligned(16))) unsigned short Qs[64 * 136];
    __shared__ __attribute__((aligned(16))) unsigned short Ks[64 * 136];
    __shared__ __attribute__((aligned(16))) unsigned short Vts[128 * 72];
    __shared__ __attribute__((aligned(16))) unsigned short Ps[4][16 * 72];
    const int tid = threadIdx.x;
    const int bt = blockIdx.y;
    const int rowBase = blockIdx.x * 64;
    const int lane = tid & 63, wave = tid >> 6;
    const int lx = lane & 15, quad = lane >> 4;

    const unsigned short* qg = qb + ((size_t)bt * BN + rowBase) * FD;
    for (int i = 0; i < 4; ++i) {
        int idx = i * 256 + tid, r = idx >> 4, c8 = idx & 15;
        *(int4*)(&Qs[r * 136 + c8 * 8]) = *(const int4*)(qg + r * FD + c8 * 8);
    }
    __syncthreads();

    s8v aq[4];
    for (int t4 = 0; t4 < 4; ++t4)
        aq[t4] = *(const s8v*)(&Qs[(wave * 16 + lx) * 136 + t4 * 32 + quad * 8]);

    f4v O[8];
    for (int gg = 0; gg < 8; ++gg) O[gg] = (f4v){0.f, 0.f, 0.f, 0.f};
    float mrow[4] = {-1e30f, -1e30f, -1e30f, -1e30f};
    float lrow[4] = {0.f, 0.f, 0.f, 0.f};

    const unsigned short* kgbase = kb + (size_t)bt * BN * FD;
    const unsigned short* vgbase = vtb + (size_t)bt * FD * BN;

    for (int ct = 0; ct < 16; ++ct) {
        __syncthreads();
        const unsigned short* kg = kgbase + (size_t)ct * 64 * FD;
        for (int i = 0; i < 4; ++i) {
            int idx = i * 256 + tid, r = idx >> 4, c8 = idx & 15;
            *(int4*)(&Ks[r * 136 + c8 * 8]) = *(const int4*)(kg + r * FD + c8 * 8);
        }
        for (int i = 0; i < 4; ++i) {
            int idx = i * 256 + tid, r = idx >> 3, c8 = idx & 7;
            *(int4*)(&Vts[r * 72 + c8 * 8]) = *(const int4*)(vgbase + (size_t)r * BN + ct * 64 + c8 * 8);
        }
        __syncthreads();

        f4v e[4];
        for (int n4 = 0; n4 < 4; ++n4) {
            f4v acc = (f4v){0.f, 0.f, 0.f, 0.f};
            for (int t4 = 0; t4 < 4; ++t4) {
                s8v bk = *(const s8v*)(&Ks[(n4 * 16 + lx) * 136 + t4 * 32 + quad * 8]);
                acc = __builtin_amdgcn_mfma_f32_16x16x32_bf16(aq[t4], bk, acc, 0, 0, 0);
            }
            for (int r = 0; r < 4; ++r) acc[r] *= SCALE;
            e[n4] = acc;
        }
        for (int r = 0; r < 4; ++r) {
            float tm = fmaxf(fmaxf(e[0][r], e[1][r]), fmaxf(e[2][r], e[3][r]));
            for (int s = 1; s < 16; s <<= 1) tm = fmaxf(tm, __shfl_xor(tm, s, 64));
            float mn = fmaxf(mrow[r], tm);
            float alpha = __expf(mrow[r] - mn);
            mrow[r] = mn;
            float ps = 0.f;
            for (int n4 = 0; n4 < 4; ++n4) {
                float p = __expf(e[n4][r] - mn);
                e[n4][r] = p;
                ps += p;
            }
            for (int s = 1; s < 16; s <<= 1) ps += __shfl_xor(ps, s, 64);
            lrow[r] = lrow[r] * alpha + ps;
            for (int gg = 0; gg < 8; ++gg) O[gg][r] *= alpha;
        }
        for (int n4 = 0; n4 < 4; ++n4)
            for (int r = 0; r < 4; ++r)
                Ps[wave][(quad * 4 + r) * 72 + n4 * 16 + lx] = f2bf(e[n4][r]);
        for (int k2 = 0; k2 < 2; ++k2) {
            s8v ap = *(const s8v*)(&Ps[wave][lx * 72 + k2 * 32 + quad * 8]);
            for (int gg = 0; gg < 8; ++gg) {
                s8v bv = *(const s8v*)(&Vts[(gg * 16 + lx) * 72 + k2 * 32 + quad * 8]);
                O[gg] = __builtin_amdgcn_mfma_f32_16x16x32_bf16(ap, bv, O[gg], 0, 0, 0);
            }
        }
    }
    const int row0 = rowBase + wave * 16 + quad * 4;
    for (int r = 0; r < 4; ++r) {
        float inv = 1.0f / lrow[r];
        for (int gg = 0; gg < 8; ++gg)
            vi[((size_t)bt * BN + row0 + r) * FD + gg * 16 + lx] = O[gg][r] * inv;
    }
}

// ---------------------------------------------------------------------------
// Kernel 7: FF1+gelu+FF2+residual+LayerNorm (round-1 verbatim fp32 code).
// ---------------------------------------------------------------------------
__global__ __launch_bounds__(256) void k_ffn(const float* __restrict__ vi,
                                             const float* __restrict__ x,
                                             const float* __restrict__ W1,
                                             const float* __restrict__ b1,
                                             const float* __restrict__ W2,
                                             const float* __restrict__ b2,
                                             const float* __restrict__ g,
                                             const float* __restrict__ lb,
                                             float* __restrict__ out) {
    __shared__ float Qs[32][132];
    __shared__ float KVs[64][132];
    const int tid = threadIdx.x;
    const int bt = blockIdx.y;
    const int rowBase = blockIdx.x * 32;
    const int tx = tid & 15, ty = tid >> 4;
    const int r0 = ty * 2, r1 = ty * 2 + 1;

    const float* vb = vi + ((size_t)bt * BN + rowBase) * FD;
    for (int i = 0; i < 4; ++i) {
        int idx = i * 256 + tid;
        int r = idx >> 5, c4 = idx & 31;
        *(float4*)(&Qs[r][c4 * 4]) = *(const float4*)(vb + (size_t)r * FD + c4 * 4);
    }

    float h0[8], h1[8];
    {
        float t0[8] = {}, t1[8] = {};
        for (int ch = 0; ch < 2; ++ch) {
            __syncthreads();
            for (int i = 0; i < 8; ++i) {
                int idx = i * 256 + tid;
                int r = idx >> 5, c4 = idx & 31;
                *(float4*)(&KVs[r][c4 * 4]) = *(const float4*)(W1 + (size_t)(ch * 64 + r) * FD + c4 * 4);
            }
            __syncthreads();
            for (int kk = 0; kk < FD; ++kk) {
                float u0 = Qs[r0][kk], u1 = Qs[r1][kk];
                for (int jj = 0; jj < 4; ++jj) {
                    int j = jj + 4 * ch;
                    float w = KVs[tx + 16 * jj][kk];
                    t0[j] += u0 * w;
                    t1[j] += u1 * w;
                }
            }
        }
        for (int j = 0; j < 8; ++j) {
            int f = tx + 16 * j;
            float bj = b1[f];
            float z0 = t0[j] + bj, z1 = t1[j] + bj;
            h0[j] = 0.5f * z0 * (1.0f + erff(z0 * GELU_K));
            h1[j] = 0.5f * z1 * (1.0f + erff(z1 * GELU_K));
        }
    }
    __syncthreads();
    for (int j = 0; j < 8; ++j) { Qs[r0][tx + 16 * j] = h0[j]; Qs[r1][tx + 16 * j] = h1[j]; }
    __syncthreads();

    float z0[8], z1[8];
    {
        float t0[8] = {}, t1[8] = {};
        for (int ch = 0; ch < 2; ++ch) {
            __syncthreads();
            for (int i = 0; i < 8; ++i) {
                int idx = i * 256 + tid;
                int r = idx >> 5, c4 = idx & 31;
                *(float4*)(&KVs[r][c4 * 4]) = *(const float4*)(W2 + (size_t)(ch * 64 + r) * FD + c4 * 4);
            }
            __syncthreads();
            for (int kk = 0; kk < FD; ++kk) {
                float u0 = Qs[r0][kk], u1 = Qs[r1][kk];
                for (int jj = 0; jj < 4; ++jj) {
                    int j = jj + 4 * ch;
                    float w = KVs[tx + 16 * jj][kk];
                    t0[j] += u0 * w;
                    t1[j] += u1 * w;
                }
            }
        }
        for (int j = 0; j < 8; ++j) {
            int f = tx + 16 * j;
            float bj = b2[f];
            z0[j] = t0[j] + bj;
            z1[j] = t1[j] + bj;
        }
    }

    const float* xb = x + ((size_t)bt * BN + rowBase) * FD;
    float res0[8], res1[8];
    float s0 = 0.f, s1 = 0.f;
    for (int j = 0; j < 8; ++j) {
        int f = tx + 16 * j;
        res0[j] = z0[j] + xb[(size_t)r0 * FD + f];
        res1[j] = z1[j] + xb[(size_t)r1 * FD + f];
        s0 += res0[j];
        s1 += res1[j];
    }
    for (int s = 1; s < 16; s <<= 1) { s0 += __shfl_xor(s0, s, 64); s1 += __shfl_xor(s1, s, 64); }
    const float mu0 = s0 * (1.0f / FD), mu1 = s1 * (1.0f / FD);
    float q0 = 0.f, q1 = 0.f;
    for (int j = 0; j < 8; ++j) {
        float d0 = res0[j] - mu0, d1 = res1[j] - mu1;
        q0 += d0 * d0;
        q1 += d1 * d1;
    }
    for (int s = 1; s < 16; s <<= 1) { q0 += __shfl_xor(q0, s, 64); q1 += __shfl_xor(q1, s, 64); }
    const float rs0 = rsqrtf(q0 * (1.0f / FD) + 1e-5f);
    const float rs1 = rsqrtf(q1 * (1.0f / FD) + 1e-5f);
    float* ob = out + ((size_t)bt * BN + rowBase) * FD;
    for (int j = 0; j < 8; ++j) {
        int f = tx + 16 * j;
        float gf = g[f], bf = lb[f];
        ob[(size_t)r0 * FD + f] = (res0[j] - mu0) * rs0 * gf + bf;
        ob[(size_t)r1 * FD + f] = (res1[j] - mu1) * rs1 * gf + bf;
    }
}

// ---------------------------------------------------------------------------
extern "C" void kernel_launch(void* const* d_in, const int* in_sizes, int n_in,
                              void* d_out, int out_size, void* d_ws, size_t ws_size,
                              hipStream_t stream) {
    const float* x     = (const float*)d_in[0];
    const float* W_xff = (const float*)d_in[1];
    const float* b_xff = (const float*)d_in[2];
    const float* W_ff1 = (const float*)d_in[3];
    const float* b_ff1 = (const float*)d_in[4];
    const float* W_ff2 = (const float*)d_in[5];
    const float* b_ff2 = (const float*)d_in[6];
    const float* ln_g  = (const float*)d_in[7];
    const float* ln_b  = (const float*)d_in[8];
    float* out = (float*)d_out;

    char* w = (char*)d_ws;
    unsigned short* qb16 = (unsigned short*)w;  w += (size_t)BTN * FD * 2;
    unsigned short* kb16 = (unsigned short*)w;  w += (size_t)BTN * FD * 2;
    unsigned short* vtb  = (unsigned short*)w;  w += (size_t)BTN * FD * 2;
    unsigned short* wxb  = (unsigned short*)w;  w += (size_t)3 * FD * FD * 2;
    // vi aliases the region holding xb/q32c/k32c/stats: all consumed before
    // k_flash writes vi (stream-ordered).
    char* alias = w;
    float* vi = (float*)alias;                  // BTN*FD*4 = 50.3 MB
    unsigned short* xb = (unsigned short*)alias; alias += (size_t)BTN * FD * 2;
    float* q32c = (float*)alias;                alias += (size_t)BB * BN * FD * 4;
    float* k32c = (float*)alias;                alias += (size_t)BB * BN * FD * 4;
    float* Mv   = (float*)alias;                alias += (size_t)BB * BN * 4;
    float* Lv   = (float*)alias;                alias += (size_t)BB * BN * 4;
    float* cs   = (float*)alias;                alias += (size_t)BB * BN * 4;
    int* ylast  = (int*)alias;

    k_convx    <<<dim3(BTN * FD / 1024), 256, 0, stream>>>(x, xb);
    k_convw    <<<dim3(192),             256, 0, stream>>>(W_xff, wxb, 3 * FD * FD);
    k_qkv_mfma <<<dim3(BTN / 64, 6),     256, 0, stream>>>(xb, wxb, b_xff, qb16, kb16, vtb);
    k_qkv32    <<<dim3(BB * 32, 4),      256, 0, stream>>>(x, W_xff, b_xff, q32c, k32c);
    k_pass1    <<<dim3(32, BB),          256, 0, stream>>>(q32c, k32c, Mv, Lv);
    k_colsum   <<<dim3(16, BB),          256, 0, stream>>>(q32c, k32c, Mv, Lv, cs);
    k_top3     <<<dim3(BB),               64, 0, stream>>>(cs, ylast);
    k_mixup    <<<dim3(FRONT_T, BB),     128, 0, stream>>>(x, W_xff, b_xff, vtb, ylast);
    k_flash    <<<dim3(16, BT),          256, 0, stream>>>(qb16, kb16, vtb, vi);
    k_ffn      <<<dim3(32, BT),          256, 0, stream>>>(vi, x, W_ff1, b_ff1, W_ff2, b_ff2,
                                                           ln_g, ln_b, out);
}